// Round 18
// baseline (465.416 us; speedup 1.0000x reference)
//
#include <hip/hip_runtime.h>
#include <hip/hip_bf16.h>
#include <math.h>

#define S_ 448
#define B_ 64
#define F_ 8
#define D_ 256
#define H_ 8
#define DK_ 32
#define L_ 4
#define PRED_ 96
#define NT_ (S_ * B_)          // 28672 tokens
#define PANEL_ (S_ * DK_)      // 14336 elems per (b,h) panel
#define VTP_ (32 * 512)        // padded transposed panel elems
#define SCQ_ 0.25503484f       // log2(e)/sqrt(32) folded into Q

typedef unsigned short bf16_t;
using bf16x8 = __attribute__((ext_vector_type(8))) short;   // 8 bf16 = 4 VGPR
using f32x4  = __attribute__((ext_vector_type(4))) float;
using f32x16 = __attribute__((ext_vector_type(16))) float;  // 32x32 MFMA acc

__device__ __forceinline__ float b2f(bf16_t b) {
  return __uint_as_float(((unsigned)b) << 16);
}
__device__ __forceinline__ bf16_t f2b(float f) {
  unsigned u = __float_as_uint(f);
  u += 0x7fffu + ((u >> 16) & 1u);     // round-to-nearest-even
  return (bf16_t)(u >> 16);
}
__device__ __forceinline__ unsigned pk2(float lo, float hi) {
  union { __hip_bfloat162 h; unsigned u; } c;
  c.h = __float22bfloat162_rn(make_float2(lo, hi));
  return c.u;
}
// async 16B global->LDS (dest is wave-uniform base + lane*16)
__device__ __forceinline__ void gload16(const bf16_t* g, char* l) {
  __builtin_amdgcn_global_load_lds(
      (const __attribute__((address_space(1))) unsigned*)g,
      (__attribute__((address_space(3))) unsigned*)l, 16, 0, 0);
}

// ---------------------------------------------------------------- embed
__global__ __launch_bounds__(256) void embed_kernel(
    const float* __restrict__ src, const float* __restrict__ w_in,
    const float* __restrict__ b_in, bf16_t* __restrict__ x) {
  int n = blockIdx.x;          // token = s*B + b
  int d = threadIdx.x;         // 0..255
  const float* srow = src + (size_t)n * F_;
  float acc = b_in[d];
#pragma unroll
  for (int f = 0; f < F_; ++f) acc += srow[f] * w_in[f * D_ + d];
  int s = n / B_;
  int i2 = d & ~1;             // 2*i
  float freq = __expf(-9.210340371976184f * (float)i2 / (float)D_);
  float ang = (float)s * freq;
  float pe = (d & 1) ? cosf(ang) : sinf(ang);
  x[(size_t)n * D_ + d] = f2b(acc + pe);
}

// ------------------------------------------- weight transpose+convert prep
__global__ __launch_bounds__(256) void transpose_w_kernel(
    const float* __restrict__ W, bf16_t* __restrict__ Wt, float scale) {
  __shared__ float t[32][33];
  int l = blockIdx.z;
  int k0 = blockIdx.x * 32, n0 = blockIdx.y * 32;
  int x = threadIdx.x, y = threadIdx.y;
  const float* src = W + ((size_t)l * 256 + k0) * 256 + n0;
#pragma unroll
  for (int i = y; i < 32; i += 8) t[i][x] = src[(size_t)i * 256 + x];
  __syncthreads();
  bf16_t* dst = Wt + ((size_t)l * 256 + n0) * 256 + k0;
#pragma unroll
  for (int i = y; i < 32; i += 8) dst[(size_t)i * 256 + x] = f2b(t[x][i] * scale);
}

// ---------------------------------------- V panel transpose: [448][32]->[32][512]
__global__ __launch_bounds__(512) void vtrans_kernel(
    const bf16_t* __restrict__ V, bf16_t* __restrict__ Vt) {
  __shared__ bf16_t t[32][456];           // 912B rows (16B aligned)
  int bh = blockIdx.x, tid = threadIdx.x;
  const bf16_t* Vp = V + (size_t)bh * PANEL_;
#pragma unroll
  for (int p = 0; p < 4; ++p) {
    int idx = tid + p * 512;
    if (idx < 1792) {
      int s = idx >> 2, c = idx & 3;
      uint4 v = *(const uint4*)(Vp + s * 32 + c * 8);
      unsigned w[4] = {v.x, v.y, v.z, v.w};
#pragma unroll
      for (int e = 0; e < 8; ++e) {
        bf16_t val = (bf16_t)((e & 1) ? (w[e >> 1] >> 16) : (w[e >> 1] & 0xffff));
        *(bf16_t*)((char*)&t[0][0] + (c * 8 + e) * 912 + s * 2) = val;
      }
    }
  }
  __syncthreads();
  bf16_t* Op = Vt + (size_t)bh * VTP_;
#pragma unroll
  for (int p = 0; p < 4; ++p) {
    int idx = tid + p * 512;              // 2048 uint4
    int dk = idx >> 6, sl = idx & 63;
    uint4 v = {0, 0, 0, 0};
    if (sl < 56) v = *(const uint4*)((char*)&t[0][0] + dk * 912 + sl * 16);
    *(uint4*)(Op + dk * 512 + sl * 8) = v;
  }
}

// ---------------------- wide GEMM: 128 rows x 256 cols (full matrix) --------
// A token-major; OLAY=1 writes head panels. 16 MFMA/wave per k-step.
template <int OLAY>
__device__ __forceinline__ void gemm_wide_body(
    const bf16_t* __restrict__ A, const bf16_t* __restrict__ Wt,
    const float* __restrict__ bias, float bscale, bf16_t* __restrict__ Y,
    int m0) {
  __shared__ char smem[49152];   // As [2][128][32] @0 16KB; Bs [2][256][32] @16384 32KB
  int tid = threadIdx.x, lane = tid & 63, wv = tid >> 6;
  int wr = wv >> 2, wc = wv & 3;       // wave: rows wr*64..+64, cols wc*64..+64
  int jg = lane >> 4, fr = lane & 15;

  auto stage = [&](int kt, int buf) {
    int k0 = kt * 32;
    int row = tid >> 2, p = tid & 3;
    int ls = p ^ ((row >> 1) & 3);
    gload16(A + (size_t)(m0 + row) * 256 + k0 + ls * 8,
            smem + buf * 8192 + wv * 1024);
    int r1 = 128 + row;
    gload16(Wt + (size_t)row * 256 + k0 + ls * 8,
            smem + 16384 + buf * 16384 + wv * 1024);
    gload16(Wt + (size_t)r1 * 256 + k0 + (p ^ ((r1 >> 1) & 3)) * 8,
            smem + 16384 + buf * 16384 + 8192 + wv * 1024);
  };

  f32x4 zero = {0.f, 0.f, 0.f, 0.f};
  f32x4 acc[4][4];
#pragma unroll
  for (int i = 0; i < 4; ++i)
#pragma unroll
    for (int j = 0; j < 4; ++j) acc[i][j] = zero;

  stage(0, 0);
  __syncthreads();

  for (int kt = 0; kt < 8; ++kt) {
    int buf = kt & 1;
    if (kt < 7) stage(kt + 1, buf ^ 1);
    bf16x8 af[4], bfr[4];
#pragma unroll
    for (int mi = 0; mi < 4; ++mi) {
      int row = wr * 64 + mi * 16 + fr;
      af[mi] = *(const bf16x8*)(smem + buf * 8192 + row * 64 +
                                ((jg ^ ((row >> 1) & 3)) << 4));
    }
#pragma unroll
    for (int ni = 0; ni < 4; ++ni) {
      int rn = wc * 64 + ni * 16 + fr;
      bfr[ni] = *(const bf16x8*)(smem + 16384 + buf * 16384 + rn * 64 +
                                 ((jg ^ ((rn >> 1) & 3)) << 4));
    }
#pragma unroll
    for (int mi = 0; mi < 4; ++mi)
#pragma unroll
      for (int ni = 0; ni < 4; ++ni)
        acc[mi][ni] = __builtin_amdgcn_mfma_f32_16x16x32_bf16(
            af[mi], bfr[ni], acc[mi][ni], 0, 0, 0);
    __syncthreads();
  }

  // ---- epilogue: per-wave LDS transpose (16 rows x 128B), 16B/lane stores
  float bcol[4];
#pragma unroll
  for (int ni = 0; ni < 4; ++ni)
    bcol[ni] = bias[wc * 64 + ni * 16 + fr] * bscale;
#pragma unroll
  for (int mi = 0; mi < 4; ++mi) {
    // double-buffer across mi via As/Bs regions (2KB per wave each)
    char* ep = smem + ((mi & 1) ? 16384 : 0) + wv * 2048;
#pragma unroll
    for (int ni = 0; ni < 4; ++ni)
#pragma unroll
      for (int r = 0; r < 4; ++r) {
        float v = acc[mi][ni][r] + bcol[ni];
        int row = jg * 4 + r;
        int cb = (ni * 16 + fr) * 2;
        *(bf16_t*)(ep + row * 128 + (cb ^ (jg << 4))) = f2b(v);
      }
    int row16 = lane >> 2;
    int n = m0 + wr * 64 + mi * 16 + row16;
#pragma unroll
    for (int ps = 0; ps < 2; ++ps) {
      int ch = (lane & 3) + ps * 4;                // 0..7 16B chunks
      uint4 v = *(uint4*)(ep + row16 * 128 +
                          ((ch * 16) ^ (((row16 >> 2) & 3) << 4)));
      if (OLAY == 0) {
        *(uint4*)((char*)(Y + (size_t)n * 256 + wc * 64) + ch * 16) = v;
      } else {
        int h = wc * 2 + (ch >> 2);                // 2 heads per wave
        *(uint4*)((char*)(Y + ((size_t)(((n & 63) << 3) | h) * S_ +
                               (n >> 6)) * DK_) +
                  (ch & 3) * 16) = v;
      }
    }
  }
}

// fused QKV: 672 blocks; one matrix per block; XCD-contiguous remap
__global__ __launch_bounds__(512, 2) void gemm_qkv_kernel(
    const bf16_t* __restrict__ A, const bf16_t* __restrict__ wq,
    const bf16_t* __restrict__ wk, const bf16_t* __restrict__ wvp,
    const float* __restrict__ bq, const float* __restrict__ bk,
    const float* __restrict__ bvp, bf16_t* __restrict__ yq,
    bf16_t* __restrict__ yk, bf16_t* __restrict__ yv) {
  int bid = blockIdx.x;
  int w = (bid & 7) * 84 + (bid >> 3);
  int mtx = w % 3;
  int m0 = (w / 3) * 128;
  const bf16_t* W = mtx == 0 ? wq : mtx == 1 ? wk : wvp;
  const float* bb = mtx == 0 ? bq : mtx == 1 ? bk : bvp;
  bf16_t* Y = mtx == 0 ? yq : mtx == 1 ? yk : yv;
  float bscale = mtx == 0 ? SCQ_ : 1.0f;
  gemm_wide_body<1>(A, W, bb, bscale, Y, m0);
}

// ---------------------- fused GEMM + bias + residual + LayerNorm ------------
// tile 64 rows x 256 cols (full row per block) -> 448 blocks.
template <int ALAY>
__global__ __launch_bounds__(512, 2) void gemm_ln_kernel(
    const bf16_t* __restrict__ A, const bf16_t* __restrict__ Wt,
    const float* __restrict__ bias, const float* __restrict__ g,
    const float* __restrict__ be, bf16_t* __restrict__ x) {
  __shared__ char smem[40960];
  // staging: As [2][64][32] @0 (8 KB); Bs [2][256][32] @8192 (32 KB)
  int tid = threadIdx.x, lane = tid & 63, wv = tid >> 6;
  int wr = wv >> 2, wc = wv & 3;       // wave: rows wr*32..+32, cols wc*64..+64
  int jg = lane >> 4, fr = lane & 15;
  int bid = blockIdx.x;
  int m0 = ((bid & 7) * 56 + (bid >> 3)) * 64;

  auto stage = [&](int kt, int buf) {
    int k0 = kt * 32;
    if (tid < 256) {                       // waves 0-3 stage A
      int row = tid >> 2, p = tid & 3;
      int ls = p ^ ((row >> 1) & 3);
      const bf16_t* ap;
      if (ALAY == 0) {
        ap = A + (size_t)(m0 + row) * 256 + k0 + ls * 8;
      } else {
        int n = m0 + row;
        int k = k0 + ls * 8;
        ap = A + ((size_t)(((n & 63) << 3) | (k >> 5)) * S_ + (n >> 6)) * DK_ +
             (k & 31);
      }
      gload16(ap, smem + buf * 4096 + wv * 1024);
    }
    int p = tid & 3;
    int r0 = tid >> 2, r1 = 128 + (tid >> 2);
    gload16(Wt + (size_t)r0 * 256 + k0 + (p ^ ((r0 >> 1) & 3)) * 8,
            smem + 8192 + buf * 16384 + wv * 1024);
    gload16(Wt + (size_t)r1 * 256 + k0 + (p ^ ((r1 >> 1) & 3)) * 8,
            smem + 8192 + buf * 16384 + 8192 + wv * 1024);
  };

  f32x4 zero = {0.f, 0.f, 0.f, 0.f};
  f32x4 acc[2][4];
#pragma unroll
  for (int i = 0; i < 2; ++i)
#pragma unroll
    for (int j = 0; j < 4; ++j) acc[i][j] = zero;

  stage(0, 0);
  __syncthreads();

  for (int kt = 0; kt < 8; ++kt) {
    int buf = kt & 1;
    if (kt < 7) stage(kt + 1, buf ^ 1);
    bf16x8 af[2], bfr[4];
#pragma unroll
    for (int mi = 0; mi < 2; ++mi) {
      int row = wr * 32 + mi * 16 + fr;
      af[mi] = *(const bf16x8*)(smem + buf * 4096 + row * 64 +
                                ((jg ^ ((row >> 1) & 3)) << 4));
    }
#pragma unroll
    for (int ni = 0; ni < 4; ++ni) {
      int rn = wc * 64 + ni * 16 + fr;
      bfr[ni] = *(const bf16x8*)(smem + 8192 + buf * 16384 + rn * 64 +
                                 ((jg ^ ((rn >> 1) & 3)) << 4));
    }
#pragma unroll
    for (int mi = 0; mi < 2; ++mi)
#pragma unroll
      for (int ni = 0; ni < 4; ++ni)
        acc[mi][ni] = __builtin_amdgcn_mfma_f32_16x16x32_bf16(
            af[mi], bfr[ni], acc[mi][ni], 0, 0, 0);
    __syncthreads();
  }

  // ---- epilogue: bias + residual, row stats, LN, transposed store
  float* ssum = (float*)smem;                 // [64][4]
  float* ssq  = (float*)(smem + 1024);        // [64][4]
  float* rowm = (float*)(smem + 2048);        // [64]
  float* rowr = (float*)(smem + 2304);        // [64]

  float bcol[4], gv[4], bev[4];
#pragma unroll
  for (int ni = 0; ni < 4; ++ni) {
    int c = wc * 64 + ni * 16 + fr;
    bcol[ni] = bias[c];
    gv[ni] = g[c];
    bev[ni] = be[c];
  }
#pragma unroll
  for (int mi = 0; mi < 2; ++mi)
#pragma unroll
    for (int r = 0; r < 4; ++r) {
      int row = wr * 32 + mi * 16 + jg * 4 + r;
      size_t gbase = (size_t)(m0 + row) * 256 + wc * 64 + fr;
      float s = 0.f, s2 = 0.f;
#pragma unroll
      for (int ni = 0; ni < 4; ++ni) {
        float v = acc[mi][ni][r] + bcol[ni] + b2f(x[gbase + ni * 16]);
        acc[mi][ni][r] = v;
        s += v;
        s2 += v * v;
      }
#pragma unroll
      for (int off = 1; off <= 8; off <<= 1) {
        s += __shfl_xor(s, off);
        s2 += __shfl_xor(s2, off);
      }
      if (fr == 0) {
        ssum[row * 4 + wc] = s;
        ssq[row * 4 + wc] = s2;
      }
    }
  __syncthreads();
  if (tid < 64) {
    float s = ssum[tid * 4] + ssum[tid * 4 + 1] + ssum[tid * 4 + 2] +
              ssum[tid * 4 + 3];
    float q = ssq[tid * 4] + ssq[tid * 4 + 1] + ssq[tid * 4 + 2] +
              ssq[tid * 4 + 3];
    float mean = s * (1.f / 256.f);
    float var = q * (1.f / 256.f) - mean * mean;
    rowm[tid] = mean;
    rowr[tid] = rsqrtf(var + 1e-5f);
  }
  __syncthreads();
  char* ep0 = smem + 8192 + wv * 2048;
#pragma unroll
  for (int mi = 0; mi < 2; ++mi) {
    char* ep = ep0 + mi * 16384;
#pragma unroll
    for (int r = 0; r < 4; ++r) {
      int row = wr * 32 + mi * 16 + jg * 4 + r;
      float mean = rowm[row], rinv = rowr[row];
#pragma unroll
      for (int ni = 0; ni < 4; ++ni) {
        float lnv = (acc[mi][ni][r] - mean) * rinv * gv[ni] + bev[ni];
        int cb = (ni * 16 + fr) * 2;
        *(bf16_t*)(ep + (jg * 4 + r) * 128 + (cb ^ (jg << 4))) = f2b(lnv);
      }
    }
    int row16 = lane >> 2;
#pragma unroll
    for (int ps = 0; ps < 2; ++ps) {
      int ch = (lane & 3) + ps * 4;
      uint4 v = *(uint4*)(ep + row16 * 128 + ((ch * 16) ^ ((row16 >> 2) << 4)));
      *(uint4*)(x + (size_t)(m0 + wr * 32 + mi * 16 + row16) * 256 + wc * 64 +
                ch * 8) = v;
    }
  }
}

// -------------- fused FFN: x = LN(x + relu(x@W1+b1)@W2 + b2) ----------------
// 448 blocks x 512 thr; h kept in LDS (As-tile format); 64 KB LDS.
__global__ __launch_bounds__(512, 2) void gemm_ffn_kernel(
    const bf16_t* __restrict__ Wt1, const float* __restrict__ b1v,
    const bf16_t* __restrict__ Wt2, const float* __restrict__ b2v,
    const float* __restrict__ g, const float* __restrict__ be,
    bf16_t* __restrict__ x) {
  __shared__ char smem[65536];
  // 0..32767  : H tiles [8][64][32] bf16 (phase-1 As staging lives @0..8KB)
  // 32768..   : Bs [2][256][32] bf16 (W1 then W2); epilogue ep buffers
  int tid = threadIdx.x, lane = tid & 63, wv = tid >> 6;
  int wr = wv >> 2, wc = wv & 3;       // wave: rows wr*32..+32, cols wc*64..+64
  int jg = lane >> 4, fr = lane & 15;
  int bid = blockIdx.x;
  int m0 = ((bid & 7) * 56 + (bid >> 3)) * 64;

  auto stageA = [&](int kt, int buf) {
    if (tid < 256) {
      int row = tid >> 2, p = tid & 3;
      int ls = p ^ ((row >> 1) & 3);
      gload16(x + (size_t)(m0 + row) * 256 + kt * 32 + ls * 8,
              smem + buf * 4096 + wv * 1024);
    }
  };
  auto stageB = [&](const bf16_t* W, int kt, int buf) {
    int p = tid & 3;
    int r0 = tid >> 2, r1 = 128 + (tid >> 2);
    gload16(W + (size_t)r0 * 256 + kt * 32 + (p ^ ((r0 >> 1) & 3)) * 8,
            smem + 32768 + buf * 16384 + wv * 1024);
    gload16(W + (size_t)r1 * 256 + kt * 32 + (p ^ ((r1 >> 1) & 3)) * 8,
            smem + 32768 + buf * 16384 + 8192 + wv * 1024);
  };

  f32x4 zero = {0.f, 0.f, 0.f, 0.f};
  f32x4 acc[2][4];
#pragma unroll
  for (int i = 0; i < 2; ++i)
#pragma unroll
    for (int j = 0; j < 4; ++j) acc[i][j] = zero;

  // ---- phase 1: h = relu(x @ W1 + b1)
  stageA(0, 0);
  stageB(Wt1, 0, 0);
  __syncthreads();
  for (int kt = 0; kt < 8; ++kt) {
    int buf = kt & 1;
    if (kt < 7) { stageA(kt + 1, buf ^ 1); stageB(Wt1, kt + 1, buf ^ 1); }
    bf16x8 af[2], bfr[4];
#pragma unroll
    for (int mi = 0; mi < 2; ++mi) {
      int row = wr * 32 + mi * 16 + fr;
      af[mi] = *(const bf16x8*)(smem + buf * 4096 + row * 64 +
                                ((jg ^ ((row >> 1) & 3)) << 4));
    }
#pragma unroll
    for (int ni = 0; ni < 4; ++ni) {
      int rn = wc * 64 + ni * 16 + fr;
      bfr[ni] = *(const bf16x8*)(smem + 32768 + buf * 16384 + rn * 64 +
                                 ((jg ^ ((rn >> 1) & 3)) << 4));
    }
#pragma unroll
    for (int mi = 0; mi < 2; ++mi)
#pragma unroll
      for (int ni = 0; ni < 4; ++ni)
        acc[mi][ni] = __builtin_amdgcn_mfma_f32_16x16x32_bf16(
            af[mi], bfr[ni], acc[mi][ni], 0, 0, 0);
    __syncthreads();
  }

  // issue W2 kt=0 staging early (Bs dead after loop-end barrier)
  stageB(Wt2, 0, 0);

  // write h into H tiles (As format + swizzle), bias + relu
  {
    float b1c[4];
#pragma unroll
    for (int ni = 0; ni < 4; ++ni) b1c[ni] = b1v[wc * 64 + ni * 16 + fr];
#pragma unroll
    for (int mi = 0; mi < 2; ++mi)
#pragma unroll
      for (int ni = 0; ni < 4; ++ni)
#pragma unroll
        for (int r = 0; r < 4; ++r) {
          float v = fmaxf(acc[mi][ni][r] + b1c[ni], 0.f);
          int row = wr * 32 + mi * 16 + jg * 4 + r;
          int col = wc * 64 + ni * 16 + fr;
          int kt2 = col >> 5, c = col & 31;
          *(bf16_t*)(smem + kt2 * 4096 + row * 64 +
                     (((c >> 3) ^ ((row >> 1) & 3)) << 4) + (c & 7) * 2) =
              f2b(v);
        }
  }
  __syncthreads();   // h visible + W2 kt=0 drained

  // ---- phase 2: y = h @ W2
  f32x4 acc2[2][4];
#pragma unroll
  for (int i = 0; i < 2; ++i)
#pragma unroll
    for (int j = 0; j < 4; ++j) acc2[i][j] = zero;

  for (int kt = 0; kt < 8; ++kt) {
    int buf = kt & 1;
    if (kt < 7) stageB(Wt2, kt + 1, buf ^ 1);
    bf16x8 af[2], bfr[4];
#pragma unroll
    for (int mi = 0; mi < 2; ++mi) {
      int row = wr * 32 + mi * 16 + fr;
      af[mi] = *(const bf16x8*)(smem + kt * 4096 + row * 64 +
                                ((jg ^ ((row >> 1) & 3)) << 4));
    }
#pragma unroll
    for (int ni = 0; ni < 4; ++ni) {
      int rn = wc * 64 + ni * 16 + fr;
      bfr[ni] = *(const bf16x8*)(smem + 32768 + buf * 16384 + rn * 64 +
                                 ((jg ^ ((rn >> 1) & 3)) << 4));
    }
#pragma unroll
    for (int mi = 0; mi < 2; ++mi)
#pragma unroll
      for (int ni = 0; ni < 4; ++ni)
        acc2[mi][ni] = __builtin_amdgcn_mfma_f32_16x16x32_bf16(
            af[mi], bfr[ni], acc2[mi][ni], 0, 0, 0);
    __syncthreads();
  }

  // ---- epilogue: bias + residual, row stats, LN, transposed store
  float* ssum = (float*)smem;                 // [64][4]
  float* ssq  = (float*)(smem + 1024);        // [64][4]
  float* rowm = (float*)(smem + 2048);        // [64]
  float* rowr = (float*)(smem + 2304);        // [64]

  float bcol[4], gv[4], bev[4];
#pragma unroll
  for (int ni = 0; ni < 4; ++ni) {
    int c = wc * 64 + ni * 16 + fr;
    bcol[ni] = b2v[c];
    gv[ni] = g[c];
    bev[ni] = be[c];
  }
#pragma unroll
  for (int mi = 0; mi < 2; ++mi)
#pragma unroll
    for (int r = 0; r < 4; ++r) {
      int row = wr * 32 + mi * 16 + jg * 4 + r;
      size_t gbase = (size_t)(m0 + row) * 256 + wc * 64 + fr;
      float s = 0.f, s2 = 0.f;
#pragma unroll
      for (int ni = 0; ni < 4; ++ni) {
        float v = acc2[mi][ni][r] + bcol[ni] + b2f(x[gbase + ni * 16]);
        acc2[mi][ni][r] = v;
        s += v;
        s2 += v * v;
      }
#pragma unroll
      for (int off = 1; off <= 8; off <<= 1) {
        s += __shfl_xor(s, off);
        s2 += __shfl_xor(s2, off);
      }
      if (fr == 0) {
        ssum[row * 4 + wc] = s;
        ssq[row * 4 + wc] = s2;
      }
    }
  __syncthreads();
  if (tid < 64) {
    float s = ssum[tid * 4] + ssum[tid * 4 + 1] + ssum[tid * 4 + 2] +
              ssum[tid * 4 + 3];
    float q = ssq[tid * 4] + ssq[tid * 4 + 1] + ssq[tid * 4 + 2] +
              ssq[tid * 4 + 3];
    float mean = s * (1.f / 256.f);
    float var = q * (1.f / 256.f) - mean * mean;
    rowm[tid] = mean;
    rowr[tid] = rsqrtf(var + 1e-5f);
  }
  __syncthreads();
  char* ep0 = smem + 32768 + wv * 2048;
#pragma unroll
  for (int mi = 0; mi < 2; ++mi) {
    char* ep = ep0 + mi * 16384;
#pragma unroll
    for (int r = 0; r < 4; ++r) {
      int row = wr * 32 + mi * 16 + jg * 4 + r;
      float mean = rowm[row], rinv = rowr[row];
#pragma unroll
      for (int ni = 0; ni < 4; ++ni) {
        float lnv = (acc2[mi][ni][r] - mean) * rinv * gv[ni] + bev[ni];
        int cb = (ni * 16 + fr) * 2;
        *(bf16_t*)(ep + (jg * 4 + r) * 128 + (cb ^ (jg << 4))) = f2b(lnv);
      }
    }
    int row16 = lane >> 2;
#pragma unroll
    for (int ps = 0; ps < 2; ++ps) {
      int ch = (lane & 3) + ps * 4;
      uint4 v = *(uint4*)(ep + row16 * 128 + ((ch * 16) ^ ((row16 >> 2) << 4)));
      *(uint4*)(x + (size_t)(m0 + wr * 32 + mi * 16 + row16) * 256 + wc * 64 +
                ch * 8) = v;
    }
  }
}

// ---------------------------------------------------------------- attention
// v10: v9 (no-max softmax) with direct in-loop loads — no named prefetch
// registers, lower pressure, compiler-scheduled hoisting.
__global__ __launch_bounds__(448) void attn_v10_kernel(
    bf16_t* __restrict__ Q, const bf16_t* __restrict__ K,
    const bf16_t* __restrict__ Vt) {
  __shared__ char Ep[7][2560];            // per-wave 32 rows x 80 B
  int tid = threadIdx.x, lane = tid & 63, wv = tid >> 6;
  int bid = blockIdx.x;
  int xcd = bid & 7, j = bid >> 3;
  int bh = ((j >> 1) << 3) | xcd;         // both halves of a bh on one XCD
  int half = j & 1;
  int q0 = (half * 7 + wv) * 32;
  bf16_t* Qp = Q + (size_t)bh * PANEL_;
  const bf16_t* Kp = K + (size_t)bh * PANEL_;
  const bf16_t* Vp = Vt + (size_t)bh * VTP_;
  int lo31 = lane & 31, hi = lane >> 5;
  const f32x16 z16 = {0.f, 0.f, 0.f, 0.f, 0.f, 0.f, 0.f, 0.f,
                      0.f, 0.f, 0.f, 0.f, 0.f, 0.f, 0.f, 0.f};

  bf16x8 qf0 = *(const bf16x8*)(Qp + (q0 + lo31) * 32 + hi * 8);
  bf16x8 qf1 = *(const bf16x8*)(Qp + (q0 + lo31) * 32 + 16 + hi * 8);

  const bf16_t* kr = Kp + lo31 * 32 + hi * 8;   // + kc*1024
  const bf16_t* vr = Vp + lo31 * 512 + hi * 8;  // + kc*32 (+16)

  float l_run = 0.f;                      // per-lane partial; final shfl once
  f32x16 o = z16;

#pragma unroll 2
  for (int kc = 0; kc < 14; ++kc) {
    bf16x8 k0 = *(const bf16x8*)(kr + kc * 1024);
    bf16x8 k1 = *(const bf16x8*)(kr + kc * 1024 + 16);
    bf16x8 v0 = *(const bf16x8*)(vr + kc * 32);
    bf16x8 v1 = *(const bf16x8*)(vr + kc * 32 + 16);
    f32x16 s = z16;
    __builtin_amdgcn_s_setprio(1);
    s = __builtin_amdgcn_mfma_f32_32x32x16_bf16(k0, qf0, s, 0, 0, 0);
    s = __builtin_amdgcn_mfma_f32_32x32x16_bf16(k1, qf1, s, 0, 0, 0);
    __builtin_amdgcn_s_setprio(0);
#pragma unroll
    for (int r = 0; r < 16; ++r) s[r] = exp2f(s[r]);
    // pairwise sum tree, accumulated per-lane (no shfl here)
    float u0 = s[0] + s[1], u1 = s[2] + s[3];
    float u2 = s[4] + s[5], u3 = s[6] + s[7];
    float u4 = s[8] + s[9], u5 = s[10] + s[11];
    float u6 = s[12] + s[13], u7 = s[14] + s[15];
    float w0 = u0 + u1, w1 = u2 + u3, w2 = u4 + u5, w3 = u6 + u7;
    l_run += (w0 + w1) + (w2 + w3);
    {
      unsigned a0 = pk2(s[0], s[1]), a1 = pk2(s[2], s[3]);
      unsigned b0 = pk2(s[4], s[5]), b1 = pk2(s[6], s[7]);
      unsigned xa0 = (unsigned)__shfl_xor((int)a0, 32);
      unsigned xa1 = (unsigned)__shfl_xor((int)a1, 32);
      unsigned xb0 = (unsigned)__shfl_xor((int)b0, 32);
      unsigned xb1 = (unsigned)__shfl_xor((int)b1, 32);
      union { unsigned u[4]; bf16x8 v; } pf;
      pf.u[0] = hi ? xb0 : a0;
      pf.u[1] = hi ? xb1 : a1;
      pf.u[2] = hi ? b0 : xa0;
      pf.u[3] = hi ? b1 : xa1;
      o = __builtin_amdgcn_mfma_f32_32x32x16_bf16(pf.v, v0, o, 0, 0, 0);
    }
    {
      unsigned a0 = pk2(s[8], s[9]), a1 = pk2(s[10], s[11]);
      unsigned b0 = pk2(s[12], s[13]), b1 = pk2(s[14], s[15]);
      unsigned xa0 = (unsigned)__shfl_xor((int)a0, 32);
      unsigned xa1 = (unsigned)__shfl_xor((int)a1, 32);
      unsigned xb0 = (unsigned)__shfl_xor((int)b0, 32);
      unsigned xb1 = (unsigned)__shfl_xor((int)b1, 32);
      union { unsigned u[4]; bf16x8 v; } pf;
      pf.u[0] = hi ? xb0 : a0;
      pf.u[1] = hi ? xb1 : a1;
      pf.u[2] = hi ? b0 : xa0;
      pf.u[3] = hi ? b1 : xa1;
      o = __builtin_amdgcn_mfma_f32_32x32x16_bf16(pf.v, v1, o, 0, 0, 0);
    }
  }

  // ---- final l reduce (one shfl) + normalize + per-wave LDS transpose
  float l_tot = l_run + __shfl_xor(l_run, 32);
  float inv = 1.f / l_tot;
  char* ep = &Ep[wv][0];
#pragma unroll
  for (int r = 0; r < 16; ++r) {
    int q = (r & 3) + 8 * (r >> 2) + 4 * hi;
    float iq = __shfl(inv, q);
    *(bf16_t*)(ep + q * 80 + lo31 * 2) = f2b(o[r] * iq);
  }
#pragma unroll
  for (int ps = 0; ps < 2; ++ps) {
    int row = ps * 16 + (lane >> 2), ch = lane & 3;
    uint4 v = *(uint4*)(ep + row * 80 + ch * 16);
    *(uint4*)(Qp + (q0 + row) * 32 + ch * 8) = v;
  }
}

// ----------------- fallback attention (unpadded V, in-LDS transpose) --------
__global__ __launch_bounds__(512) void attn_v3f_kernel(
    bf16_t* __restrict__ Q, const bf16_t* __restrict__ K,
    const bf16_t* __restrict__ Vsrc) {
  __shared__ bf16_t Vt[32][520];
  __shared__ char Pbuf[8][2048];
  int tid = threadIdx.x, lane = tid & 63, wv = tid >> 6;
  int bid = blockIdx.x;
  int bh = (bid & 7) | ((bid >> 5) << 3);
  int chunk = (bid >> 3) & 3;
  bf16_t* Qp = Q + (size_t)bh * PANEL_;
  const bf16_t* Kp = K + (size_t)bh * PANEL_;
  int jg = lane >> 4, fr = lane & 15;

  const bf16_t* Vp = Vsrc + (size_t)bh * PANEL_;
  for (int idx = tid; idx < 448 * 4; idx += 512) {
    int t = idx >> 2, c = idx & 3;
    uint4 vv = *(const uint4*)(Vp + t * 32 + c * 8);
    unsigned w[4] = {vv.x, vv.y, vv.z, vv.w};
#pragma unroll
    for (int e = 0; e < 8; ++e) {
      bf16_t val = (bf16_t)((e & 1) ? (w[e >> 1] >> 16) : (w[e >> 1] & 0xffff));
      *(bf16_t*)((char*)&Vt[0][0] + (c * 8 + e) * 1040 + t * 2) = val;
    }
  }
  __syncthreads();

  int q0 = chunk * 128 + wv * 16;
  if (q0 < S_) {
    f32x4 zero = {0.f, 0.f, 0.f, 0.f};
    bf16x8 qf = *(const bf16x8*)(Qp + (q0 + fr) * 32 + jg * 8);
    f32x4 s2[28];
#pragma unroll
    for (int ct = 0; ct < 28; ++ct) {
      bf16x8 kf = *(const bf16x8*)(Kp + (ct * 16 + fr) * 32 + jg * 8);
      s2[ct] = __builtin_amdgcn_mfma_f32_16x16x32_bf16(kf, qf, zero, 0, 0, 0);
    }
    float m = s2[0][0];
#pragma unroll
    for (int ct = 0; ct < 28; ++ct)
#pragma unroll
      for (int r = 0; r < 4; ++r) m = fmaxf(m, s2[ct][r]);
    m = fmaxf(m, __shfl_xor(m, 16));
    m = fmaxf(m, __shfl_xor(m, 32));
    float l = 0.f;
#pragma unroll
    for (int ct = 0; ct < 28; ++ct)
#pragma unroll
      for (int r = 0; r < 4; ++r) {
        float p = exp2f(s2[ct][r] - m);
        s2[ct][r] = p;
        l += p;
      }
    l += __shfl_xor(l, 16);
    l += __shfl_xor(l, 32);
    float inv = 1.f / l;

    char* pb0 = &Pbuf[wv][0];
    f32x4 o[2] = {zero, zero};
#pragma unroll
    for (int c = 0; c < 14; ++c) {
      char* pb = pb0 + (c & 1) * 1024;
      uint2 w0, w1;
      w0.x = pk2(s2[2 * c][0], s2[2 * c][1]);
      w0.y = pk2(s2[2 * c][2], s2[2 * c][3]);
      w1.x = pk2(s2[2 * c + 1][0], s2[2 * c + 1][1]);
      w1.y = pk2(s2[2 * c + 1][2], s2[2 * c + 1][3]);
      *(uint2*)(pb + fr * 64 + 8 * jg) = w0;
      *(uint2*)(pb + fr * 64 + 32 + 8 * jg) = w1;
      bf16x8 pf = *(const bf16x8*)(pb + fr * 64 + jg * 16);
#pragma unroll
      for (int nt = 0; nt < 2; ++nt) {
        bf16x8 vf = *(const bf16x8*)((const char*)&Vt[0][0] +
                                     (nt * 16 + fr) * 1040 +
                                     (c * 32 + jg * 8) * 2);
        o[nt] = __builtin_amdgcn_mfma_f32_16x16x32_bf16(pf, vf, o[nt], 0, 0, 0);
      }
    }
    float invq[4];
#pragma unroll
    for (int r = 0; r < 4; ++r) invq[r] = __shfl(inv, jg * 4 + r);
#pragma unroll
    for (int nt = 0; nt < 2; ++nt)
#pragma unroll
      for (int r = 0; r < 4; ++r) {
        float v = o[nt][r] * invq[r];
        int row = jg * 4 + r;
        int cb = (nt * 16 + fr) * 2;
        *(bf16_t*)(pb0 + row * 64 + (cb ^ (jg << 4))) = f2b(v);
      }
    {
      int row16 = lane >> 2, c = lane & 3;
      uint4 v = *(uint4*)(pb0 + row16 * 64 +
                          ((c << 4) ^ (((row16 >> 2) & 3) << 4)));
      *(uint4*)(Qp + (q0 + row16) * 32 + c * 8) = v;
    }
  }
}

// ---------------------------------------------------------------- out proj
__global__ __launch_bounds__(256) void out_kernel(
    const bf16_t* __restrict__ x, const float* __restrict__ w_out,
    const float* __restrict__ b_out, float* __restrict__ out) {
  int idx = blockIdx.x * 256 + threadIdx.x;  // (p*B+b)*F + f
  int f = idx & 7;
  int pb = idx >> 3;
  const bf16_t* xrow = x + ((size_t)(S_ - PRED_) * B_ + pb) * D_;
  float acc = b_out[f];
  for (int dd = 0; dd < D_; ++dd) acc += b2f(xrow[dd]) * w_out[dd * F_ + f];
  out[idx] = acc;
}

// ---------------------------------------------------------------- launch
extern "C" void kernel_launch(void* const* d_in, const int* in_sizes, int n_in,
                              void* d_out, int out_size, void* d_ws, size_t ws_size,
                              hipStream_t stream) {
  const float* src  = (const float*)d_in[0];
  const float* w_in = (const float*)d_in[1];
  const float* b_in = (const float*)d_in[2];
  const float* Wq = (const float*)d_in[3];
  const float* bq = (const float*)d_in[4];
  const float* Wk = (const float*)d_in[5];
  const float* bk = (const float*)d_in[6];
  const float* Wv = (const float*)d_in[7];
  const float* bv = (const float*)d_in[8];
  const float* Wo = (const float*)d_in[9];
  const float* bo = (const float*)d_in[10];
  const float* g1 = (const float*)d_in[11];
  const float* be1 = (const float*)d_in[12];
  const float* W1 = (const float*)d_in[13];
  const float* b1 = (const float*)d_in[14];
  const float* W2 = (const float*)d_in[15];
  const float* b2 = (const float*)d_in[16];
  const float* g2 = (const float*)d_in[17];
  const float* be2 = (const float*)d_in[18];
  const float* w_out = (const float*)d_in[19];
  const float* b_out = (const float*)d_in[20];
  float* out = (float*)d_out;

  const size_t NTD = (size_t)NT_ * D_;
  bf16_t* xb = (bf16_t*)d_ws;        // token-major [n][256]
  bf16_t* qb = xb + NTD;             // panels [(b,h)][448][32]
  bf16_t* kb = qb + NTD;
  bf16_t* vb = kb + NTD;
  bf16_t* wt = vb + NTD;             // 6 * L * 65536 bf16 = 3.1 MB
  const size_t WSZ = (size_t)L_ * 65536;
  bf16_t* wtq = wt;
  bf16_t* wtk = wtq + WSZ;
  bf16_t* wtv = wtk + WSZ;
  bf16_t* wto = wtv + WSZ;
  bf16_t* wt1 = wto + WSZ;
  bf16_t* wt2 = wt1 + WSZ;
  bf16_t* vtb = wt2 + WSZ;           // transposed V panels, 16.8 MB

  const size_t NEED = ((size_t)4 * NTD + 6 * WSZ + (size_t)512 * VTP_) * 2;
  const int use_vt = (ws_size >= NEED) ? 1 : 0;

  dim3 tb(32, 8), tg(8, 8, L_);
  transpose_w_kernel<<<tg, tb, 0, stream>>>(Wq, wtq, SCQ_);
  transpose_w_kernel<<<tg, tb, 0, stream>>>(Wk, wtk, 1.0f);
  transpose_w_kernel<<<tg, tb, 0, stream>>>(Wv, wtv, 1.0f);
  transpose_w_kernel<<<tg, tb, 0, stream>>>(Wo, wto, 1.0f);
  transpose_w_kernel<<<tg, tb, 0, stream>>>(W1, wt1, 1.0f);
  transpose_w_kernel<<<tg, tb, 0, stream>>>(W2, wt2, 1.0f);

  embed_kernel<<<NT_, 256, 0, stream>>>(src, w_in, b_in, xb);

  for (int l = 0; l < L_; ++l) {
    const size_t woff = (size_t)l * 65536;
    const size_t boff = (size_t)l * D_;
    gemm_qkv_kernel<<<672, 512, 0, stream>>>(
        xb, wtq + woff, wtk + woff, wtv + woff, bq + boff, bk + boff,
        bv + boff, qb, kb, vb);
    if (use_vt) {
      vtrans_kernel<<<512, 512, 0, stream>>>(vb, vtb);
      attn_v10_kernel<<<1024, 448, 0, stream>>>(qb, kb, vtb);
    } else {
      attn_v3f_kernel<<<2048, 512, 0, stream>>>(qb, kb, vb);
    }
    gemm_ln_kernel<1><<<448, 512, 0, stream>>>(qb, wto + woff, bo + boff,
                                               g1 + boff, be1 + boff, xb);
    gemm_ffn_kernel<<<448, 512, 0, stream>>>(wt1 + woff, b1 + boff,
                                             wt2 + woff, b2 + boff,
                                             g2 + boff, be2 + boff, xb);
  }

  out_kernel<<<(PRED_ * B_ * F_) / 256, 256, 0, stream>>>(xb, w_out, b_out, out);
}

// Round 19
// 464.977 us; speedup vs baseline: 1.0009x; 1.0009x over previous
//
#include <hip/hip_runtime.h>
#include <hip/hip_bf16.h>
#include <math.h>

#define S_ 448
#define B_ 64
#define F_ 8
#define D_ 256
#define H_ 8
#define DK_ 32
#define L_ 4
#define PRED_ 96
#define NT_ (S_ * B_)          // 28672 tokens
#define PANEL_ (S_ * DK_)      // 14336 elems per (b,h) panel
#define VTP_ (32 * 512)        // padded transposed panel elems
#define SCQ_ 0.25503484f       // log2(e)/sqrt(32) folded into Q

typedef unsigned short bf16_t;
using bf16x8 = __attribute__((ext_vector_type(8))) short;   // 8 bf16 = 4 VGPR
using f32x4  = __attribute__((ext_vector_type(4))) float;
using f32x16 = __attribute__((ext_vector_type(16))) float;  // 32x32 MFMA acc

__device__ __forceinline__ float b2f(bf16_t b) {
  return __uint_as_float(((unsigned)b) << 16);
}
__device__ __forceinline__ bf16_t f2b(float f) {
  unsigned u = __float_as_uint(f);
  u += 0x7fffu + ((u >> 16) & 1u);     // round-to-nearest-even
  return (bf16_t)(u >> 16);
}
__device__ __forceinline__ unsigned pk2(float lo, float hi) {
  union { __hip_bfloat162 h; unsigned u; } c;
  c.h = __float22bfloat162_rn(make_float2(lo, hi));
  return c.u;
}
// async 16B global->LDS (dest is wave-uniform base + lane*16)
__device__ __forceinline__ void gload16(const bf16_t* g, char* l) {
  __builtin_amdgcn_global_load_lds(
      (const __attribute__((address_space(1))) unsigned*)g,
      (__attribute__((address_space(3))) unsigned*)l, 16, 0, 0);
}

// ---------------------------------------------------------------- embed
__global__ __launch_bounds__(256) void embed_kernel(
    const float* __restrict__ src, const float* __restrict__ w_in,
    const float* __restrict__ b_in, bf16_t* __restrict__ x) {
  int n = blockIdx.x;          // token = s*B + b
  int d = threadIdx.x;         // 0..255
  const float* srow = src + (size_t)n * F_;
  float acc = b_in[d];
#pragma unroll
  for (int f = 0; f < F_; ++f) acc += srow[f] * w_in[f * D_ + d];
  int s = n / B_;
  int i2 = d & ~1;             // 2*i
  float freq = __expf(-9.210340371976184f * (float)i2 / (float)D_);
  float ang = (float)s * freq;
  float pe = (d & 1) ? cosf(ang) : sinf(ang);
  x[(size_t)n * D_ + d] = f2b(acc + pe);
}

// ------------------------------------------- weight transpose+convert prep
__global__ __launch_bounds__(256) void transpose_w_kernel(
    const float* __restrict__ W, bf16_t* __restrict__ Wt, float scale) {
  __shared__ float t[32][33];
  int l = blockIdx.z;
  int k0 = blockIdx.x * 32, n0 = blockIdx.y * 32;
  int x = threadIdx.x, y = threadIdx.y;
  const float* src = W + ((size_t)l * 256 + k0) * 256 + n0;
#pragma unroll
  for (int i = y; i < 32; i += 8) t[i][x] = src[(size_t)i * 256 + x];
  __syncthreads();
  bf16_t* dst = Wt + ((size_t)l * 256 + n0) * 256 + k0;
#pragma unroll
  for (int i = y; i < 32; i += 8) dst[(size_t)i * 256 + x] = f2b(t[x][i] * scale);
}

// ---------------------------------------- V panel transpose: [448][32]->[32][512]
__global__ __launch_bounds__(512) void vtrans_kernel(
    const bf16_t* __restrict__ V, bf16_t* __restrict__ Vt) {
  __shared__ bf16_t t[32][456];           // 912B rows (16B aligned)
  int bh = blockIdx.x, tid = threadIdx.x;
  const bf16_t* Vp = V + (size_t)bh * PANEL_;
#pragma unroll
  for (int p = 0; p < 4; ++p) {
    int idx = tid + p * 512;
    if (idx < 1792) {
      int s = idx >> 2, c = idx & 3;
      uint4 v = *(const uint4*)(Vp + s * 32 + c * 8);
      unsigned w[4] = {v.x, v.y, v.z, v.w};
#pragma unroll
      for (int e = 0; e < 8; ++e) {
        bf16_t val = (bf16_t)((e & 1) ? (w[e >> 1] >> 16) : (w[e >> 1] & 0xffff));
        *(bf16_t*)((char*)&t[0][0] + (c * 8 + e) * 912 + s * 2) = val;
      }
    }
  }
  __syncthreads();
  bf16_t* Op = Vt + (size_t)bh * VTP_;
#pragma unroll
  for (int p = 0; p < 4; ++p) {
    int idx = tid + p * 512;              // 2048 uint4
    int dk = idx >> 6, sl = idx & 63;
    uint4 v = {0, 0, 0, 0};
    if (sl < 56) v = *(const uint4*)((char*)&t[0][0] + dk * 912 + sl * 16);
    *(uint4*)(Op + dk * 512 + sl * 8) = v;
  }
}

// ---------------------- wide GEMM: 128 rows x 256 cols (full matrix) --------
// A token-major; OLAY=1 writes head panels. 16 MFMA/wave per k-step.
template <int OLAY>
__device__ __forceinline__ void gemm_wide_body(
    const bf16_t* __restrict__ A, const bf16_t* __restrict__ Wt,
    const float* __restrict__ bias, float bscale, bf16_t* __restrict__ Y,
    int m0) {
  __shared__ char smem[49152];   // As [2][128][32] @0 16KB; Bs [2][256][32] @16384 32KB
  int tid = threadIdx.x, lane = tid & 63, wv = tid >> 6;
  int wr = wv >> 2, wc = wv & 3;       // wave: rows wr*64..+64, cols wc*64..+64
  int jg = lane >> 4, fr = lane & 15;

  auto stage = [&](int kt, int buf) {
    int k0 = kt * 32;
    int row = tid >> 2, p = tid & 3;
    int ls = p ^ ((row >> 1) & 3);
    gload16(A + (size_t)(m0 + row) * 256 + k0 + ls * 8,
            smem + buf * 8192 + wv * 1024);
    int r1 = 128 + row;
    gload16(Wt + (size_t)row * 256 + k0 + ls * 8,
            smem + 16384 + buf * 16384 + wv * 1024);
    gload16(Wt + (size_t)r1 * 256 + k0 + (p ^ ((r1 >> 1) & 3)) * 8,
            smem + 16384 + buf * 16384 + 8192 + wv * 1024);
  };

  f32x4 zero = {0.f, 0.f, 0.f, 0.f};
  f32x4 acc[4][4];
#pragma unroll
  for (int i = 0; i < 4; ++i)
#pragma unroll
    for (int j = 0; j < 4; ++j) acc[i][j] = zero;

  stage(0, 0);
  __syncthreads();

  for (int kt = 0; kt < 8; ++kt) {
    int buf = kt & 1;
    if (kt < 7) stage(kt + 1, buf ^ 1);
    bf16x8 af[4], bfr[4];
#pragma unroll
    for (int mi = 0; mi < 4; ++mi) {
      int row = wr * 64 + mi * 16 + fr;
      af[mi] = *(const bf16x8*)(smem + buf * 8192 + row * 64 +
                                ((jg ^ ((row >> 1) & 3)) << 4));
    }
#pragma unroll
    for (int ni = 0; ni < 4; ++ni) {
      int rn = wc * 64 + ni * 16 + fr;
      bfr[ni] = *(const bf16x8*)(smem + 16384 + buf * 16384 + rn * 64 +
                                 ((jg ^ ((rn >> 1) & 3)) << 4));
    }
#pragma unroll
    for (int mi = 0; mi < 4; ++mi)
#pragma unroll
      for (int ni = 0; ni < 4; ++ni)
        acc[mi][ni] = __builtin_amdgcn_mfma_f32_16x16x32_bf16(
            af[mi], bfr[ni], acc[mi][ni], 0, 0, 0);
    __syncthreads();
  }

  // ---- epilogue: per-wave LDS transpose (16 rows x 128B), 16B/lane stores
  float bcol[4];
#pragma unroll
  for (int ni = 0; ni < 4; ++ni)
    bcol[ni] = bias[wc * 64 + ni * 16 + fr] * bscale;
#pragma unroll
  for (int mi = 0; mi < 4; ++mi) {
    // double-buffer across mi via As/Bs regions (2KB per wave each)
    char* ep = smem + ((mi & 1) ? 16384 : 0) + wv * 2048;
#pragma unroll
    for (int ni = 0; ni < 4; ++ni)
#pragma unroll
      for (int r = 0; r < 4; ++r) {
        float v = acc[mi][ni][r] + bcol[ni];
        int row = jg * 4 + r;
        int cb = (ni * 16 + fr) * 2;
        *(bf16_t*)(ep + row * 128 + (cb ^ (jg << 4))) = f2b(v);
      }
    int row16 = lane >> 2;
    int n = m0 + wr * 64 + mi * 16 + row16;
#pragma unroll
    for (int ps = 0; ps < 2; ++ps) {
      int ch = (lane & 3) + ps * 4;                // 0..7 16B chunks
      uint4 v = *(uint4*)(ep + row16 * 128 +
                          ((ch * 16) ^ (((row16 >> 2) & 3) << 4)));
      if (OLAY == 0) {
        *(uint4*)((char*)(Y + (size_t)n * 256 + wc * 64) + ch * 16) = v;
      } else {
        int h = wc * 2 + (ch >> 2);                // 2 heads per wave
        *(uint4*)((char*)(Y + ((size_t)(((n & 63) << 3) | h) * S_ +
                               (n >> 6)) * DK_) +
                  (ch & 3) * 16) = v;
      }
    }
  }
}

// fused QKV: 672 blocks; one matrix per block; XCD-contiguous remap
__global__ __launch_bounds__(512, 2) void gemm_qkv_kernel(
    const bf16_t* __restrict__ A, const bf16_t* __restrict__ wq,
    const bf16_t* __restrict__ wk, const bf16_t* __restrict__ wvp,
    const float* __restrict__ bq, const float* __restrict__ bk,
    const float* __restrict__ bvp, bf16_t* __restrict__ yq,
    bf16_t* __restrict__ yk, bf16_t* __restrict__ yv) {
  int bid = blockIdx.x;
  int w = (bid & 7) * 84 + (bid >> 3);
  int mtx = w % 3;
  int m0 = (w / 3) * 128;
  const bf16_t* W = mtx == 0 ? wq : mtx == 1 ? wk : wvp;
  const float* bb = mtx == 0 ? bq : mtx == 1 ? bk : bvp;
  bf16_t* Y = mtx == 0 ? yq : mtx == 1 ? yk : yv;
  float bscale = mtx == 0 ? SCQ_ : 1.0f;
  gemm_wide_body<1>(A, W, bb, bscale, Y, m0);
}

// ---------------------- fused GEMM + bias + residual + LayerNorm ------------
// tile 64 rows x 256 cols (full row per block) -> 448 blocks.
template <int ALAY>
__global__ __launch_bounds__(512, 2) void gemm_ln_kernel(
    const bf16_t* __restrict__ A, const bf16_t* __restrict__ Wt,
    const float* __restrict__ bias, const float* __restrict__ g,
    const float* __restrict__ be, bf16_t* __restrict__ x) {
  __shared__ char smem[40960];
  // staging: As [2][64][32] @0 (8 KB); Bs [2][256][32] @8192 (32 KB)
  int tid = threadIdx.x, lane = tid & 63, wv = tid >> 6;
  int wr = wv >> 2, wc = wv & 3;       // wave: rows wr*32..+32, cols wc*64..+64
  int jg = lane >> 4, fr = lane & 15;
  int bid = blockIdx.x;
  int m0 = ((bid & 7) * 56 + (bid >> 3)) * 64;

  auto stage = [&](int kt, int buf) {
    int k0 = kt * 32;
    if (tid < 256) {                       // waves 0-3 stage A
      int row = tid >> 2, p = tid & 3;
      int ls = p ^ ((row >> 1) & 3);
      const bf16_t* ap;
      if (ALAY == 0) {
        ap = A + (size_t)(m0 + row) * 256 + k0 + ls * 8;
      } else {
        int n = m0 + row;
        int k = k0 + ls * 8;
        ap = A + ((size_t)(((n & 63) << 3) | (k >> 5)) * S_ + (n >> 6)) * DK_ +
             (k & 31);
      }
      gload16(ap, smem + buf * 4096 + wv * 1024);
    }
    int p = tid & 3;
    int r0 = tid >> 2, r1 = 128 + (tid >> 2);
    gload16(Wt + (size_t)r0 * 256 + k0 + (p ^ ((r0 >> 1) & 3)) * 8,
            smem + 8192 + buf * 16384 + wv * 1024);
    gload16(Wt + (size_t)r1 * 256 + k0 + (p ^ ((r1 >> 1) & 3)) * 8,
            smem + 8192 + buf * 16384 + 8192 + wv * 1024);
  };

  f32x4 zero = {0.f, 0.f, 0.f, 0.f};
  f32x4 acc[2][4];
#pragma unroll
  for (int i = 0; i < 2; ++i)
#pragma unroll
    for (int j = 0; j < 4; ++j) acc[i][j] = zero;

  stage(0, 0);
  __syncthreads();

  for (int kt = 0; kt < 8; ++kt) {
    int buf = kt & 1;
    if (kt < 7) stage(kt + 1, buf ^ 1);
    bf16x8 af[2], bfr[4];
#pragma unroll
    for (int mi = 0; mi < 2; ++mi) {
      int row = wr * 32 + mi * 16 + fr;
      af[mi] = *(const bf16x8*)(smem + buf * 4096 + row * 64 +
                                ((jg ^ ((row >> 1) & 3)) << 4));
    }
#pragma unroll
    for (int ni = 0; ni < 4; ++ni) {
      int rn = wc * 64 + ni * 16 + fr;
      bfr[ni] = *(const bf16x8*)(smem + 8192 + buf * 16384 + rn * 64 +
                                 ((jg ^ ((rn >> 1) & 3)) << 4));
    }
#pragma unroll
    for (int mi = 0; mi < 2; ++mi)
#pragma unroll
      for (int ni = 0; ni < 4; ++ni)
        acc[mi][ni] = __builtin_amdgcn_mfma_f32_16x16x32_bf16(
            af[mi], bfr[ni], acc[mi][ni], 0, 0, 0);
    __syncthreads();
  }

  // ---- epilogue: bias + residual, row stats, LN, transposed store
  float* ssum = (float*)smem;                 // [64][4]
  float* ssq  = (float*)(smem + 1024);        // [64][4]
  float* rowm = (float*)(smem + 2048);        // [64]
  float* rowr = (float*)(smem + 2304);        // [64]

  float bcol[4], gv[4], bev[4];
#pragma unroll
  for (int ni = 0; ni < 4; ++ni) {
    int c = wc * 64 + ni * 16 + fr;
    bcol[ni] = bias[c];
    gv[ni] = g[c];
    bev[ni] = be[c];
  }
#pragma unroll
  for (int mi = 0; mi < 2; ++mi)
#pragma unroll
    for (int r = 0; r < 4; ++r) {
      int row = wr * 32 + mi * 16 + jg * 4 + r;
      size_t gbase = (size_t)(m0 + row) * 256 + wc * 64 + fr;
      float s = 0.f, s2 = 0.f;
#pragma unroll
      for (int ni = 0; ni < 4; ++ni) {
        float v = acc[mi][ni][r] + bcol[ni] + b2f(x[gbase + ni * 16]);
        acc[mi][ni][r] = v;
        s += v;
        s2 += v * v;
      }
#pragma unroll
      for (int off = 1; off <= 8; off <<= 1) {
        s += __shfl_xor(s, off);
        s2 += __shfl_xor(s2, off);
      }
      if (fr == 0) {
        ssum[row * 4 + wc] = s;
        ssq[row * 4 + wc] = s2;
      }
    }
  __syncthreads();
  if (tid < 64) {
    float s = ssum[tid * 4] + ssum[tid * 4 + 1] + ssum[tid * 4 + 2] +
              ssum[tid * 4 + 3];
    float q = ssq[tid * 4] + ssq[tid * 4 + 1] + ssq[tid * 4 + 2] +
              ssq[tid * 4 + 3];
    float mean = s * (1.f / 256.f);
    float var = q * (1.f / 256.f) - mean * mean;
    rowm[tid] = mean;
    rowr[tid] = rsqrtf(var + 1e-5f);
  }
  __syncthreads();
  char* ep0 = smem + 8192 + wv * 2048;
#pragma unroll
  for (int mi = 0; mi < 2; ++mi) {
    char* ep = ep0 + mi * 16384;
#pragma unroll
    for (int r = 0; r < 4; ++r) {
      int row = wr * 32 + mi * 16 + jg * 4 + r;
      float mean = rowm[row], rinv = rowr[row];
#pragma unroll
      for (int ni = 0; ni < 4; ++ni) {
        float lnv = (acc[mi][ni][r] - mean) * rinv * gv[ni] + bev[ni];
        int cb = (ni * 16 + fr) * 2;
        *(bf16_t*)(ep + (jg * 4 + r) * 128 + (cb ^ (jg << 4))) = f2b(lnv);
      }
    }
    int row16 = lane >> 2;
#pragma unroll
    for (int ps = 0; ps < 2; ++ps) {
      int ch = (lane & 3) + ps * 4;
      uint4 v = *(uint4*)(ep + row16 * 128 + ((ch * 16) ^ ((row16 >> 2) << 4)));
      *(uint4*)(x + (size_t)(m0 + wr * 32 + mi * 16 + row16) * 256 + wc * 64 +
                ch * 8) = v;
    }
  }
}

// -------------- fused FFN: x = LN(x + relu(x@W1+b1)@W2 + b2) ----------------
// 448 blocks x 512 thr; h kept in LDS (As-tile format); 64 KB LDS.
__global__ __launch_bounds__(512, 2) void gemm_ffn_kernel(
    const bf16_t* __restrict__ Wt1, const float* __restrict__ b1v,
    const bf16_t* __restrict__ Wt2, const float* __restrict__ b2v,
    const float* __restrict__ g, const float* __restrict__ be,
    bf16_t* __restrict__ x) {
  __shared__ char smem[65536];
  // 0..32767  : H tiles [8][64][32] bf16 (phase-1 As staging lives @0..8KB)
  // 32768..   : Bs [2][256][32] bf16 (W1 then W2); epilogue ep buffers
  int tid = threadIdx.x, lane = tid & 63, wv = tid >> 6;
  int wr = wv >> 2, wc = wv & 3;       // wave: rows wr*32..+32, cols wc*64..+64
  int jg = lane >> 4, fr = lane & 15;
  int bid = blockIdx.x;
  int m0 = ((bid & 7) * 56 + (bid >> 3)) * 64;

  auto stageA = [&](int kt, int buf) {
    if (tid < 256) {
      int row = tid >> 2, p = tid & 3;
      int ls = p ^ ((row >> 1) & 3);
      gload16(x + (size_t)(m0 + row) * 256 + kt * 32 + ls * 8,
              smem + buf * 4096 + wv * 1024);
    }
  };
  auto stageB = [&](const bf16_t* W, int kt, int buf) {
    int p = tid & 3;
    int r0 = tid >> 2, r1 = 128 + (tid >> 2);
    gload16(W + (size_t)r0 * 256 + kt * 32 + (p ^ ((r0 >> 1) & 3)) * 8,
            smem + 32768 + buf * 16384 + wv * 1024);
    gload16(W + (size_t)r1 * 256 + kt * 32 + (p ^ ((r1 >> 1) & 3)) * 8,
            smem + 32768 + buf * 16384 + 8192 + wv * 1024);
  };

  f32x4 zero = {0.f, 0.f, 0.f, 0.f};
  f32x4 acc[2][4];
#pragma unroll
  for (int i = 0; i < 2; ++i)
#pragma unroll
    for (int j = 0; j < 4; ++j) acc[i][j] = zero;

  // ---- phase 1: h = relu(x @ W1 + b1)
  stageA(0, 0);
  stageB(Wt1, 0, 0);
  __syncthreads();
  for (int kt = 0; kt < 8; ++kt) {
    int buf = kt & 1;
    if (kt < 7) { stageA(kt + 1, buf ^ 1); stageB(Wt1, kt + 1, buf ^ 1); }
    bf16x8 af[2], bfr[4];
#pragma unroll
    for (int mi = 0; mi < 2; ++mi) {
      int row = wr * 32 + mi * 16 + fr;
      af[mi] = *(const bf16x8*)(smem + buf * 4096 + row * 64 +
                                ((jg ^ ((row >> 1) & 3)) << 4));
    }
#pragma unroll
    for (int ni = 0; ni < 4; ++ni) {
      int rn = wc * 64 + ni * 16 + fr;
      bfr[ni] = *(const bf16x8*)(smem + 32768 + buf * 16384 + rn * 64 +
                                 ((jg ^ ((rn >> 1) & 3)) << 4));
    }
#pragma unroll
    for (int mi = 0; mi < 2; ++mi)
#pragma unroll
      for (int ni = 0; ni < 4; ++ni)
        acc[mi][ni] = __builtin_amdgcn_mfma_f32_16x16x32_bf16(
            af[mi], bfr[ni], acc[mi][ni], 0, 0, 0);
    __syncthreads();
  }

  // issue W2 kt=0 staging early (Bs dead after loop-end barrier)
  stageB(Wt2, 0, 0);

  // write h into H tiles (As format + swizzle), bias + relu
  {
    float b1c[4];
#pragma unroll
    for (int ni = 0; ni < 4; ++ni) b1c[ni] = b1v[wc * 64 + ni * 16 + fr];
#pragma unroll
    for (int mi = 0; mi < 2; ++mi)
#pragma unroll
      for (int ni = 0; ni < 4; ++ni)
#pragma unroll
        for (int r = 0; r < 4; ++r) {
          float v = fmaxf(acc[mi][ni][r] + b1c[ni], 0.f);
          int row = wr * 32 + mi * 16 + jg * 4 + r;
          int col = wc * 64 + ni * 16 + fr;
          int kt2 = col >> 5, c = col & 31;
          *(bf16_t*)(smem + kt2 * 4096 + row * 64 +
                     (((c >> 3) ^ ((row >> 1) & 3)) << 4) + (c & 7) * 2) =
              f2b(v);
        }
  }
  __syncthreads();   // h visible + W2 kt=0 drained

  // ---- phase 2: y = h @ W2
  f32x4 acc2[2][4];
#pragma unroll
  for (int i = 0; i < 2; ++i)
#pragma unroll
    for (int j = 0; j < 4; ++j) acc2[i][j] = zero;

  for (int kt = 0; kt < 8; ++kt) {
    int buf = kt & 1;
    if (kt < 7) stageB(Wt2, kt + 1, buf ^ 1);
    bf16x8 af[2], bfr[4];
#pragma unroll
    for (int mi = 0; mi < 2; ++mi) {
      int row = wr * 32 + mi * 16 + fr;
      af[mi] = *(const bf16x8*)(smem + kt * 4096 + row * 64 +
                                ((jg ^ ((row >> 1) & 3)) << 4));
    }
#pragma unroll
    for (int ni = 0; ni < 4; ++ni) {
      int rn = wc * 64 + ni * 16 + fr;
      bfr[ni] = *(const bf16x8*)(smem + 32768 + buf * 16384 + rn * 64 +
                                 ((jg ^ ((rn >> 1) & 3)) << 4));
    }
#pragma unroll
    for (int mi = 0; mi < 2; ++mi)
#pragma unroll
      for (int ni = 0; ni < 4; ++ni)
        acc2[mi][ni] = __builtin_amdgcn_mfma_f32_16x16x32_bf16(
            af[mi], bfr[ni], acc2[mi][ni], 0, 0, 0);
    __syncthreads();
  }

  // ---- epilogue: bias + residual, row stats, LN, transposed store
  float* ssum = (float*)smem;                 // [64][4]
  float* ssq  = (float*)(smem + 1024);        // [64][4]
  float* rowm = (float*)(smem + 2048);        // [64]
  float* rowr = (float*)(smem + 2304);        // [64]

  float bcol[4], gv[4], bev[4];
#pragma unroll
  for (int ni = 0; ni < 4; ++ni) {
    int c = wc * 64 + ni * 16 + fr;
    bcol[ni] = b2v[c];
    gv[ni] = g[c];
    bev[ni] = be[c];
  }
#pragma unroll
  for (int mi = 0; mi < 2; ++mi)
#pragma unroll
    for (int r = 0; r < 4; ++r) {
      int row = wr * 32 + mi * 16 + jg * 4 + r;
      size_t gbase = (size_t)(m0 + row) * 256 + wc * 64 + fr;
      float s = 0.f, s2 = 0.f;
#pragma unroll
      for (int ni = 0; ni < 4; ++ni) {
        float v = acc2[mi][ni][r] + bcol[ni] + b2f(x[gbase + ni * 16]);
        acc2[mi][ni][r] = v;
        s += v;
        s2 += v * v;
      }
#pragma unroll
      for (int off = 1; off <= 8; off <<= 1) {
        s += __shfl_xor(s, off);
        s2 += __shfl_xor(s2, off);
      }
      if (fr == 0) {
        ssum[row * 4 + wc] = s;
        ssq[row * 4 + wc] = s2;
      }
    }
  __syncthreads();
  if (tid < 64) {
    float s = ssum[tid * 4] + ssum[tid * 4 + 1] + ssum[tid * 4 + 2] +
              ssum[tid * 4 + 3];
    float q = ssq[tid * 4] + ssq[tid * 4 + 1] + ssq[tid * 4 + 2] +
              ssq[tid * 4 + 3];
    float mean = s * (1.f / 256.f);
    float var = q * (1.f / 256.f) - mean * mean;
    rowm[tid] = mean;
    rowr[tid] = rsqrtf(var + 1e-5f);
  }
  __syncthreads();
  char* ep0 = smem + 32768 + wv * 2048;
#pragma unroll
  for (int mi = 0; mi < 2; ++mi) {
    char* ep = ep0 + mi * 16384;
#pragma unroll
    for (int r = 0; r < 4; ++r) {
      int row = wr * 32 + mi * 16 + jg * 4 + r;
      float mean = rowm[row], rinv = rowr[row];
#pragma unroll
      for (int ni = 0; ni < 4; ++ni) {
        float lnv = (acc2[mi][ni][r] - mean) * rinv * gv[ni] + bev[ni];
        int cb = (ni * 16 + fr) * 2;
        *(bf16_t*)(ep + (jg * 4 + r) * 128 + (cb ^ (jg << 4))) = f2b(lnv);
      }
    }
    int row16 = lane >> 2;
#pragma unroll
    for (int ps = 0; ps < 2; ++ps) {
      int ch = (lane & 3) + ps * 4;
      uint4 v = *(uint4*)(ep + row16 * 128 + ((ch * 16) ^ ((row16 >> 2) << 4)));
      *(uint4*)(x + (size_t)(m0 + wr * 32 + mi * 16 + row16) * 256 + wc * 64 +
                ch * 8) = v;
    }
  }
}

// ---------------------------------------------------------------- attention
// v11: v10 with __launch_bounds__(448, 4) -> 128 unified regs/lane, keeping
// MFMA accumulators + softmax state in true VGPRs (no accvgpr shuttling).
__global__ __launch_bounds__(448, 4) void attn_v11_kernel(
    bf16_t* __restrict__ Q, const bf16_t* __restrict__ K,
    const bf16_t* __restrict__ Vt) {
  __shared__ char Ep[7][2560];            // per-wave 32 rows x 80 B
  int tid = threadIdx.x, lane = tid & 63, wv = tid >> 6;
  int bid = blockIdx.x;
  int xcd = bid & 7, j = bid >> 3;
  int bh = ((j >> 1) << 3) | xcd;         // both halves of a bh on one XCD
  int half = j & 1;
  int q0 = (half * 7 + wv) * 32;
  bf16_t* Qp = Q + (size_t)bh * PANEL_;
  const bf16_t* Kp = K + (size_t)bh * PANEL_;
  const bf16_t* Vp = Vt + (size_t)bh * VTP_;
  int lo31 = lane & 31, hi = lane >> 5;
  const f32x16 z16 = {0.f, 0.f, 0.f, 0.f, 0.f, 0.f, 0.f, 0.f,
                      0.f, 0.f, 0.f, 0.f, 0.f, 0.f, 0.f, 0.f};

  bf16x8 qf0 = *(const bf16x8*)(Qp + (q0 + lo31) * 32 + hi * 8);
  bf16x8 qf1 = *(const bf16x8*)(Qp + (q0 + lo31) * 32 + 16 + hi * 8);

  const bf16_t* kr = Kp + lo31 * 32 + hi * 8;   // + kc*1024
  const bf16_t* vr = Vp + lo31 * 512 + hi * 8;  // + kc*32 (+16)

  float l_run = 0.f;                      // per-lane partial; final shfl once
  f32x16 o = z16;

#pragma unroll 2
  for (int kc = 0; kc < 14; ++kc) {
    bf16x8 k0 = *(const bf16x8*)(kr + kc * 1024);
    bf16x8 k1 = *(const bf16x8*)(kr + kc * 1024 + 16);
    bf16x8 v0 = *(const bf16x8*)(vr + kc * 32);
    bf16x8 v1 = *(const bf16x8*)(vr + kc * 32 + 16);
    f32x16 s = z16;
    __builtin_amdgcn_s_setprio(1);
    s = __builtin_amdgcn_mfma_f32_32x32x16_bf16(k0, qf0, s, 0, 0, 0);
    s = __builtin_amdgcn_mfma_f32_32x32x16_bf16(k1, qf1, s, 0, 0, 0);
    __builtin_amdgcn_s_setprio(0);
#pragma unroll
    for (int r = 0; r < 16; ++r) s[r] = exp2f(s[r]);
    // pairwise sum tree, accumulated per-lane (no shfl here)
    float u0 = s[0] + s[1], u1 = s[2] + s[3];
    float u2 = s[4] + s[5], u3 = s[6] + s[7];
    float u4 = s[8] + s[9], u5 = s[10] + s[11];
    float u6 = s[12] + s[13], u7 = s[14] + s[15];
    float w0 = u0 + u1, w1 = u2 + u3, w2 = u4 + u5, w3 = u6 + u7;
    l_run += (w0 + w1) + (w2 + w3);
    {
      unsigned a0 = pk2(s[0], s[1]), a1 = pk2(s[2], s[3]);
      unsigned b0 = pk2(s[4], s[5]), b1 = pk2(s[6], s[7]);
      unsigned xa0 = (unsigned)__shfl_xor((int)a0, 32);
      unsigned xa1 = (unsigned)__shfl_xor((int)a1, 32);
      unsigned xb0 = (unsigned)__shfl_xor((int)b0, 32);
      unsigned xb1 = (unsigned)__shfl_xor((int)b1, 32);
      union { unsigned u[4]; bf16x8 v; } pf;
      pf.u[0] = hi ? xb0 : a0;
      pf.u[1] = hi ? xb1 : a1;
      pf.u[2] = hi ? b0 : xa0;
      pf.u[3] = hi ? b1 : xa1;
      o = __builtin_amdgcn_mfma_f32_32x32x16_bf16(pf.v, v0, o, 0, 0, 0);
    }
    {
      unsigned a0 = pk2(s[8], s[9]), a1 = pk2(s[10], s[11]);
      unsigned b0 = pk2(s[12], s[13]), b1 = pk2(s[14], s[15]);
      unsigned xa0 = (unsigned)__shfl_xor((int)a0, 32);
      unsigned xa1 = (unsigned)__shfl_xor((int)a1, 32);
      unsigned xb0 = (unsigned)__shfl_xor((int)b0, 32);
      unsigned xb1 = (unsigned)__shfl_xor((int)b1, 32);
      union { unsigned u[4]; bf16x8 v; } pf;
      pf.u[0] = hi ? xb0 : a0;
      pf.u[1] = hi ? xb1 : a1;
      pf.u[2] = hi ? b0 : xa0;
      pf.u[3] = hi ? b1 : xa1;
      o = __builtin_amdgcn_mfma_f32_32x32x16_bf16(pf.v, v1, o, 0, 0, 0);
    }
  }

  // ---- final l reduce (one shfl) + normalize + per-wave LDS transpose
  float l_tot = l_run + __shfl_xor(l_run, 32);
  float inv = 1.f / l_tot;
  char* ep = &Ep[wv][0];
#pragma unroll
  for (int r = 0; r < 16; ++r) {
    int q = (r & 3) + 8 * (r >> 2) + 4 * hi;
    float iq = __shfl(inv, q);
    *(bf16_t*)(ep + q * 80 + lo31 * 2) = f2b(o[r] * iq);
  }
#pragma unroll
  for (int ps = 0; ps < 2; ++ps) {
    int row = ps * 16 + (lane >> 2), ch = lane & 3;
    uint4 v = *(uint4*)(ep + row * 80 + ch * 16);
    *(uint4*)(Qp + (q0 + row) * 32 + ch * 8) = v;
  }
}

// ----------------- fallback attention (unpadded V, in-LDS transpose) --------
__global__ __launch_bounds__(512) void attn_v3f_kernel(
    bf16_t* __restrict__ Q, const bf16_t* __restrict__ K,
    const bf16_t* __restrict__ Vsrc) {
  __shared__ bf16_t Vt[32][520];
  __shared__ char Pbuf[8][2048];
  int tid = threadIdx.x, lane = tid & 63, wv = tid >> 6;
  int bid = blockIdx.x;
  int bh = (bid & 7) | ((bid >> 5) << 3);
  int chunk = (bid >> 3) & 3;
  bf16_t* Qp = Q + (size_t)bh * PANEL_;
  const bf16_t* Kp = K + (size_t)bh * PANEL_;
  int jg = lane >> 4, fr = lane & 15;

  const bf16_t* Vp = Vsrc + (size_t)bh * PANEL_;
  for (int idx = tid; idx < 448 * 4; idx += 512) {
    int t = idx >> 2, c = idx & 3;
    uint4 vv = *(const uint4*)(Vp + t * 32 + c * 8);
    unsigned w[4] = {vv.x, vv.y, vv.z, vv.w};
#pragma unroll
    for (int e = 0; e < 8; ++e) {
      bf16_t val = (bf16_t)((e & 1) ? (w[e >> 1] >> 16) : (w[e >> 1] & 0xffff));
      *(bf16_t*)((char*)&Vt[0][0] + (c * 8 + e) * 1040 + t * 2) = val;
    }
  }
  __syncthreads();

  int q0 = chunk * 128 + wv * 16;
  if (q0 < S_) {
    f32x4 zero = {0.f, 0.f, 0.f, 0.f};
    bf16x8 qf = *(const bf16x8*)(Qp + (q0 + fr) * 32 + jg * 8);
    f32x4 s2[28];
#pragma unroll
    for (int ct = 0; ct < 28; ++ct) {
      bf16x8 kf = *(const bf16x8*)(Kp + (ct * 16 + fr) * 32 + jg * 8);
      s2[ct] = __builtin_amdgcn_mfma_f32_16x16x32_bf16(kf, qf, zero, 0, 0, 0);
    }
    float m = s2[0][0];
#pragma unroll
    for (int ct = 0; ct < 28; ++ct)
#pragma unroll
      for (int r = 0; r < 4; ++r) m = fmaxf(m, s2[ct][r]);
    m = fmaxf(m, __shfl_xor(m, 16));
    m = fmaxf(m, __shfl_xor(m, 32));
    float l = 0.f;
#pragma unroll
    for (int ct = 0; ct < 28; ++ct)
#pragma unroll
      for (int r = 0; r < 4; ++r) {
        float p = exp2f(s2[ct][r] - m);
        s2[ct][r] = p;
        l += p;
      }
    l += __shfl_xor(l, 16);
    l += __shfl_xor(l, 32);
    float inv = 1.f / l;

    char* pb0 = &Pbuf[wv][0];
    f32x4 o[2] = {zero, zero};
#pragma unroll
    for (int c = 0; c < 14; ++c) {
      char* pb = pb0 + (c & 1) * 1024;
      uint2 w0, w1;
      w0.x = pk2(s2[2 * c][0], s2[2 * c][1]);
      w0.y = pk2(s2[2 * c][2], s2[2 * c][3]);
      w1.x = pk2(s2[2 * c + 1][0], s2[2 * c + 1][1]);
      w1.y = pk2(s2[2 * c + 1][2], s2[2 * c + 1][3]);
      *(uint2*)(pb + fr * 64 + 8 * jg) = w0;
      *(uint2*)(pb + fr * 64 + 32 + 8 * jg) = w1;
      bf16x8 pf = *(const bf16x8*)(pb + fr * 64 + jg * 16);
#pragma unroll
      for (int nt = 0; nt < 2; ++nt) {
        bf16x8 vf = *(const bf16x8*)((const char*)&Vt[0][0] +
                                     (nt * 16 + fr) * 1040 +
                                     (c * 32 + jg * 8) * 2);
        o[nt] = __builtin_amdgcn_mfma_f32_16x16x32_bf16(pf, vf, o[nt], 0, 0, 0);
      }
    }
    float invq[4];
#pragma unroll
    for (int r = 0; r < 4; ++r) invq[r] = __shfl(inv, jg * 4 + r);
#pragma unroll
    for (int nt = 0; nt < 2; ++nt)
#pragma unroll
      for (int r = 0; r < 4; ++r) {
        float v = o[nt][r] * invq[r];
        int row = jg * 4 + r;
        int cb = (nt * 16 + fr) * 2;
        *(bf16_t*)(pb0 + row * 64 + (cb ^ (jg << 4))) = f2b(v);
      }
    {
      int row16 = lane >> 2, c = lane & 3;
      uint4 v = *(uint4*)(pb0 + row16 * 64 +
                          ((c << 4) ^ (((row16 >> 2) & 3) << 4)));
      *(uint4*)(Qp + (q0 + row16) * 32 + c * 8) = v;
    }
  }
}

// ---------------------------------------------------------------- out proj
__global__ __launch_bounds__(256) void out_kernel(
    const bf16_t* __restrict__ x, const float* __restrict__ w_out,
    const float* __restrict__ b_out, float* __restrict__ out) {
  int idx = blockIdx.x * 256 + threadIdx.x;  // (p*B+b)*F + f
  int f = idx & 7;
  int pb = idx >> 3;
  const bf16_t* xrow = x + ((size_t)(S_ - PRED_) * B_ + pb) * D_;
  float acc = b_out[f];
  for (int dd = 0; dd < D_; ++dd) acc += b2f(xrow[dd]) * w_out[dd * F_ + f];
  out[idx] = acc;
}

// ---------------------------------------------------------------- launch
extern "C" void kernel_launch(void* const* d_in, const int* in_sizes, int n_in,
                              void* d_out, int out_size, void* d_ws, size_t ws_size,
                              hipStream_t stream) {
  const float* src  = (const float*)d_in[0];
  const float* w_in = (const float*)d_in[1];
  const float* b_in = (const float*)d_in[2];
  const float* Wq = (const float*)d_in[3];
  const float* bq = (const float*)d_in[4];
  const float* Wk = (const float*)d_in[5];
  const float* bk = (const float*)d_in[6];
  const float* Wv = (const float*)d_in[7];
  const float* bv = (const float*)d_in[8];
  const float* Wo = (const float*)d_in[9];
  const float* bo = (const float*)d_in[10];
  const float* g1 = (const float*)d_in[11];
  const float* be1 = (const float*)d_in[12];
  const float* W1 = (const float*)d_in[13];
  const float* b1 = (const float*)d_in[14];
  const float* W2 = (const float*)d_in[15];
  const float* b2 = (const float*)d_in[16];
  const float* g2 = (const float*)d_in[17];
  const float* be2 = (const float*)d_in[18];
  const float* w_out = (const float*)d_in[19];
  const float* b_out = (const float*)d_in[20];
  float* out = (float*)d_out;

  const size_t NTD = (size_t)NT_ * D_;
  bf16_t* xb = (bf16_t*)d_ws;        // token-major [n][256]
  bf16_t* qb = xb + NTD;             // panels [(b,h)][448][32]
  bf16_t* kb = qb + NTD;
  bf16_t* vb = kb + NTD;
  bf16_t* wt = vb + NTD;             // 6 * L * 65536 bf16 = 3.1 MB
  const size_t WSZ = (size_t)L_ * 65536;
  bf16_t* wtq = wt;
  bf16_t* wtk = wtq + WSZ;
  bf16_t* wtv = wtk + WSZ;
  bf16_t* wto = wtv + WSZ;
  bf16_t* wt1 = wto + WSZ;
  bf16_t* wt2 = wt1 + WSZ;
  bf16_t* vtb = wt2 + WSZ;           // transposed V panels, 16.8 MB

  const size_t NEED = ((size_t)4 * NTD + 6 * WSZ + (size_t)512 * VTP_) * 2;
  const int use_vt = (ws_size >= NEED) ? 1 : 0;

  dim3 tb(32, 8), tg(8, 8, L_);
  transpose_w_kernel<<<tg, tb, 0, stream>>>(Wq, wtq, SCQ_);
  transpose_w_kernel<<<tg, tb, 0, stream>>>(Wk, wtk, 1.0f);
  transpose_w_kernel<<<tg, tb, 0, stream>>>(Wv, wtv, 1.0f);
  transpose_w_kernel<<<tg, tb, 0, stream>>>(Wo, wto, 1.0f);
  transpose_w_kernel<<<tg, tb, 0, stream>>>(W1, wt1, 1.0f);
  transpose_w_kernel<<<tg, tb, 0, stream>>>(W2, wt2, 1.0f);

  embed_kernel<<<NT_, 256, 0, stream>>>(src, w_in, b_in, xb);

  for (int l = 0; l < L_; ++l) {
    const size_t woff = (size_t)l * 65536;
    const size_t boff = (size_t)l * D_;
    gemm_qkv_kernel<<<672, 512, 0, stream>>>(
        xb, wtq + woff, wtk + woff, wtv + woff, bq + boff, bk + boff,
        bv + boff, qb, kb, vb);
    if (use_vt) {
      vtrans_kernel<<<512, 512, 0, stream>>>(vb, vtb);
      attn_v11_kernel<<<1024, 448, 0, stream>>>(qb, kb, vtb);
    } else {
      attn_v3f_kernel<<<2048, 512, 0, stream>>>(qb, kb, vb);
    }
    gemm_ln_kernel<1><<<448, 512, 0, stream>>>(qb, wto + woff, bo + boff,
                                               g1 + boff, be1 + boff, xb);
    gemm_ffn_kernel<<<448, 512, 0, stream>>>(wt1 + woff, b1 + boff,
                                             wt2 + woff, b2 + boff,
                                             g2 + boff, be2 + boff, xb);
  }

  out_kernel<<<(PRED_ * B_ * F_) / 256, 256, 0, stream>>>(xb, w_out, b_out, out);
}